// Round 1
// 79320.062 us; speedup vs baseline: 3.8574x; 3.8574x over previous
//
#include <hip/hip_runtime.h>
#include <math.h>

// Deep Reservoir Memory Network forward, MI355X persistent-dataflow kernel.
// Round 1: weights resident in LDS + software-pipelined state staging.
//
// Structure: ONE persistent kernel, 256 blocks x 512 threads, 5 dataflow sets
// (same flag protocol as round 0). NEW this round:
//   * Each block's recurrent-weight slice (128 KB) is loaded into LDS ONCE
//     before the t-loop. Round 0 streamed 32 MB of weights per tick through
//     a 4.2 MB/XCD L2 working set -> ~15.5 MB/tick HBM/LLC refetch, weight
//     loads at ~700+ cy latency on every dot chunk. Now weights come from
//     LDS with immediate-offset ds_read_b128 (padded rows, conflict-free).
//   * State staging (sc1/LLC loads) is software-pipelined: the next 128-float
//     chunk is loaded into registers while the current chunk is consumed.
//     Barriers inside the dot pipeline are lgkm-only (s_waitcnt lgkmcnt(0) +
//     raw s_barrier) so the vm prefetch stays in flight across them
//     (__syncthreads would drain vmcnt(0) and kill the overlap).
//
// Sets (blockIdx.x):
//   [0,32)    M1 : m1_new = m1_old@Vm1^T + x_t@Wm1^T          (32 cols/blk)
//   [32,96)   M2 : m2_new = m2_old@Vm2^T + m1_new@Wm2^T       (16 cols/blk)
//   [96,160)  H1 : h1_new = .5*h1 + .5*tanh(x@Win1^T + h1@Wh1^T
//                                           + m2_new@Wmh1^T + b1)
//   [160,224) H2 : h2_new = .5*h2 + .5*tanh(g2a + h1_new@Win2^T
//                                           + m2_new@Wmh2^T)   (+ write out)
//   [224,256) G2 : g2a = h2_old@Wh2^T + b2                     (32 cols/blk)
//
// LDS plan (dynamic, 147968 B = 144.5 KiB, 1 block/CU):
//   float4 w4[8192]  : 128 KiB weight slice, granule (k4,c) at [mat*4096 + k4*C + c]
//   float4 sbuf[1056]: 16.5 KiB state chunk, 32 rows x 33 granules (pad +1
//                      granule/row -> 4 consecutive rows hit disjoint banks)

#define BB 32
#define TT 2048
#define II 64
#define MM 1024
#define HHH 1024
#define ALEAK 0.5f
#define NTHREADS 512
#define SPIN_CAP 5000

#define SCOPE __HIP_MEMORY_SCOPE_AGENT

typedef unsigned long long u64;

__device__ __forceinline__ float lda(const float* p) {
  return __hip_atomic_load(p, __ATOMIC_RELAXED, SCOPE);
}
__device__ __forceinline__ u64 lda64(const u64* p) {
  return __hip_atomic_load(p, __ATOMIC_RELAXED, SCOPE);
}
__device__ __forceinline__ void sta(float* p, float v) {
  __hip_atomic_store(p, v, __ATOMIC_RELAXED, SCOPE);
}

// lane0 spins on a device-scope flag; capped so a sync bug can't hang the GPU.
__device__ __forceinline__ void wait_flag(int* f, int target) {
  if (threadIdx.x == 0) {
    int it = 0;
    while (__hip_atomic_load(f, __ATOMIC_RELAXED, SCOPE) < target) {
      __builtin_amdgcn_s_sleep(2);
      if (++it > SPIN_CAP) break;  // fail loud (wrong answer), not a timeout
    }
  }
  __syncthreads();
}

__device__ __forceinline__ void post_flag(int* f) {
  __syncthreads();  // drains each wave's vmcnt -> all sc1 stores at LLC
  if (threadIdx.x == 0) {
    __hip_atomic_fetch_add(f, 1, __ATOMIC_RELEASE, SCOPE);
  }
}

// lgkm-only barrier: orders LDS reads/writes across the block WITHOUT
// draining vmcnt, so prefetched global (sc1) loads stay in flight.
// asm memory clobbers on both sides pin all memory ops to their side.
__device__ __forceinline__ void barrier_lds() {
  asm volatile("s_waitcnt lgkmcnt(0)" ::: "memory");
  __builtin_amdgcn_s_barrier();
  asm volatile("" ::: "memory");
}

union Q2 { u64 q[2]; float4 f; };
struct Stage {
  Q2 a, b;
  __device__ __forceinline__ void load(const u64* src) {
    a.q[0] = lda64(src + 0); a.q[1] = lda64(src + 1);
    b.q[0] = lda64(src + 2); b.q[1] = lda64(src + 3);
  }
};

// K=64 input-projection dot: x-row . Wrow (both global, cached)
__device__ __forceinline__ float dot_x(const float* __restrict__ xrow,
                                       const float* __restrict__ Wrow) {
  float a = 0.f;
  #pragma unroll
  for (int k = 0; k < II; k += 4) {
    float4 w = *(const float4*)(Wrow + k);
    float4 s = *(const float4*)(xrow + k);
    a += w.x * s.x + w.y * s.y + w.z * s.z + w.w * s.w;
  }
  return a;
}

// ---- weight preload: global -> LDS, once per kernel ----
// layout identity: w4[idx], idx = mat*4096 + k4*C + c  <-  W_mat[n0+c][4*k4..]
__device__ __forceinline__ void load_w2(float4* w4, const float* __restrict__ W0,
                                        const float* __restrict__ W1, int n0,
                                        int tid) {
  #pragma unroll
  for (int i = 0; i < 16; ++i) {
    int idx = tid + i * NTHREADS;
    const float* W = (i < 8) ? W0 : W1;  // idx<4096 <=> i<8
    int j = idx & 4095;
    w4[idx] = *(const float4*)(W + (size_t)(n0 + (j & 15)) * 1024 + (j >> 4) * 4);
  }
}
__device__ __forceinline__ void load_w1(float4* w4, const float* __restrict__ W,
                                        int n0, int tid) {
  #pragma unroll
  for (int i = 0; i < 16; ++i) {
    int idx = tid + i * NTHREADS;
    w4[idx] = *(const float4*)(W + (size_t)(n0 + (idx & 31)) * 1024 + (idx >> 5) * 4);
  }
}

// ---- pipelined 1024-dot, C=16 cols/block (1 row x 1 col per thread) ----
// Returns sum_k S[bg][k] * Wlds[c][k]. All 512 threads participate in staging.
__device__ __forceinline__ float matdot16(const float* __restrict__ S,
                                          const float4* __restrict__ wmat,
                                          float4* __restrict__ sbuf, int tid) {
  const int c = tid & 15;
  const int bg = tid >> 4;           // compute row == staging row
  const int g0 = c * 2;              // this thread stages granules g0,g0+1
  const u64* src = (const u64*)(S + (size_t)bg * 1024) + g0 * 2;
  const int ws0 = bg * 33 + g0;
  const float4* sb = sbuf + bg * 33;
  const float4* wb = wmat + c;
  Stage st;
  st.load(src);  // chunk 0
  float acc = 0.f;
  for (int ch = 0; ch < 8; ++ch) {
    barrier_lds();                         // readers of prev chunk done
    sbuf[ws0] = st.a.f;
    sbuf[ws0 + 1] = st.b.f;
    if (ch < 7) st.load(src + (ch + 1) * 64);  // prefetch next (vm, crosses barrier)
    barrier_lds();                         // chunk visible
    const float4* wcb = wb + (ch << 9);    // ch*32*16 granules
    float a0 = 0.f, a1 = 0.f;
    #pragma unroll 4
    for (int k4 = 0; k4 < 32; k4 += 2) {
      float4 s0 = sb[k4];
      float4 w0 = wcb[(k4) << 4];
      float4 s1 = sb[k4 + 1];
      float4 w1 = wcb[(k4 + 1) << 4];
      a0 = fmaf(s0.x, w0.x, a0); a0 = fmaf(s0.y, w0.y, a0);
      a0 = fmaf(s0.z, w0.z, a0); a0 = fmaf(s0.w, w0.w, a0);
      a1 = fmaf(s1.x, w1.x, a1); a1 = fmaf(s1.y, w1.y, a1);
      a1 = fmaf(s1.z, w1.z, a1); a1 = fmaf(s1.w, w1.w, a1);
    }
    acc += a0 + a1;
  }
  return acc;
}

// ---- pipelined 1024-dot, C=32 cols/block (2 rows x 1 col per thread) ----
__device__ __forceinline__ void matdot32(const float* __restrict__ S,
                                         const float4* __restrict__ w4,
                                         float4* __restrict__ sbuf, int tid,
                                         float& O0, float& O1) {
  const int c = tid & 31;
  const int rp = tid >> 5;           // rows rp, rp+16
  const int tr = tid >> 4;           // staging row
  const int g0 = (tid & 15) * 2;
  const u64* src = (const u64*)(S + (size_t)tr * 1024) + g0 * 2;
  const int ws0 = tr * 33 + g0;
  const float4* sb0 = sbuf + rp * 33;
  const float4* sb1 = sbuf + (rp + 16) * 33;
  const float4* wb = w4 + c;
  Stage st;
  st.load(src);
  float A0 = 0.f, A1 = 0.f;
  for (int ch = 0; ch < 8; ++ch) {
    barrier_lds();
    sbuf[ws0] = st.a.f;
    sbuf[ws0 + 1] = st.b.f;
    if (ch < 7) st.load(src + (ch + 1) * 64);
    barrier_lds();
    const float4* wcb = wb + (ch << 10);   // ch*32*32 granules
    #pragma unroll 4
    for (int k4 = 0; k4 < 32; ++k4) {
      float4 w = wcb[k4 << 5];
      float4 s0 = sb0[k4];
      float4 s1 = sb1[k4];
      A0 = fmaf(s0.x, w.x, A0); A0 = fmaf(s0.y, w.y, A0);
      A0 = fmaf(s0.z, w.z, A0); A0 = fmaf(s0.w, w.w, A0);
      A1 = fmaf(s1.x, w.x, A1); A1 = fmaf(s1.y, w.y, A1);
      A1 = fmaf(s1.z, w.z, A1); A1 = fmaf(s1.w, w.w, A1);
    }
  }
  O0 += A0;
  O1 += A1;
}

__global__ __launch_bounds__(NTHREADS) void drmn_persistent(
    const float* __restrict__ x, const float* __restrict__ Wm1,
    const float* __restrict__ Vm1, const float* __restrict__ Wm2,
    const float* __restrict__ Vm2, const float* __restrict__ Win1,
    const float* __restrict__ Wh1, const float* __restrict__ Wmh1,
    const float* __restrict__ b1, const float* __restrict__ Win2,
    const float* __restrict__ Wh2, const float* __restrict__ Wmh2,
    const float* __restrict__ b2, float* __restrict__ out, float* ws,
    int* flags) {
  extern __shared__ float4 smem[];
  float4* w4 = smem;             // [8192] weight granules (128 KiB)
  float4* sbuf = smem + 8192;    // [1056] state chunk, 32 x 33 granules

  const int blk = blockIdx.x;
  const int tid = threadIdx.x;

  float* m1s = ws;                  // [2][B][M]
  float* m2s = m1s + 2 * BB * MM;   // [2][B][M]
  float* h1s = m2s + 2 * BB * MM;   // [2][B][H]
  float* h2s = h1s + 2 * BB * MM;   // [2][B][H]
  float* g2a = h2s + 2 * BB * MM;   // [B][H]

  int* m1c = flags;            // each [T]
  int* m2c = m1c + TT;
  int* h1c = m2c + TT;
  int* h2c = h1c + TT;
  int* g2c = h2c + TT;

  if (blk < 32) {
    // ================= M1 =================
    const int c = tid & 31;
    const int n = blk * 32 + c;
    const int r0 = tid >> 5, r1 = r0 + 16;
    load_w1(w4, Vm1, blk * 32, tid);
    __syncthreads();
    const float* wx = Wm1 + (size_t)n * II;
    for (int t = 0; t < TT; ++t) {
      const float* rd = m1s + (t & 1) * BB * MM;
      float* wr = m1s + ((t & 1) ^ 1) * BB * MM;
      if (t >= 1) wait_flag(&m1c[t - 1], 32);   // full prev state readable
      if (t >= 2) wait_flag(&m2c[t - 2], 64);   // consumer of write-buffer done
      float a0 = dot_x(x + ((size_t)r0 * TT + t) * II, wx);
      float a1 = dot_x(x + ((size_t)r1 * TT + t) * II, wx);
      matdot32(rd, w4, sbuf, tid, a0, a1);
      sta(wr + (size_t)r0 * MM + n, a0);
      sta(wr + (size_t)r1 * MM + n, a1);
      post_flag(&m1c[t]);
    }
  } else if (blk < 96) {
    // ================= M2 =================
    const int sb_ = blk - 32;
    const int c = tid & 15, bg = tid >> 4;
    const int n = sb_ * 16 + c;
    load_w2(w4, Vm2, Wm2, sb_ * 16, tid);
    __syncthreads();
    for (int t = 0; t < TT; ++t) {
      const float* rd = m2s + (t & 1) * BB * MM;
      float* wr = m2s + ((t & 1) ^ 1) * BB * MM;
      const float* rdm1 = m1s + ((t & 1) ^ 1) * BB * MM;  // m1_new (this tick)
      if (t >= 1) wait_flag(&m2c[t - 1], 64);
      if (t >= 2) {
        wait_flag(&h1c[t - 2], 64);
        wait_flag(&h2c[t - 2], 64);
      }
      float a = matdot16(rd, w4, sbuf, tid);          // Vm2 part
      wait_flag(&m1c[t], 32);
      a += matdot16(rdm1, w4 + 4096, sbuf, tid);      // Wm2 part
      sta(wr + (size_t)bg * MM + n, a);
      post_flag(&m2c[t]);
    }
  } else if (blk < 160) {
    // ================= H1 =================
    const int sb_ = blk - 96;
    const int c = tid & 15, bg = tid >> 4;
    const int n = sb_ * 16 + c;
    load_w2(w4, Wh1, Wmh1, sb_ * 16, tid);
    __syncthreads();
    const float* wi = Win1 + (size_t)n * II;
    const float bias = b1[n];
    float h1reg = 0.f;  // this thread's own h1[bg][n]
    for (int t = 0; t < TT; ++t) {
      const float* rdh = h1s + (t & 1) * BB * HHH;
      float* wrh = h1s + ((t & 1) ^ 1) * BB * HHH;
      const float* rdm2 = m2s + ((t & 1) ^ 1) * BB * MM;  // m2_new
      if (t >= 1) wait_flag(&h1c[t - 1], 64);
      if (t >= 2) wait_flag(&h2c[t - 2], 64);
      float a = bias + dot_x(x + ((size_t)bg * TT + t) * II, wi);
      a += matdot16(rdh, w4, sbuf, tid);              // Wh1 part (own state)
      wait_flag(&m2c[t], 64);
      a += matdot16(rdm2, w4 + 4096, sbuf, tid);      // Wmh1 part
      float h1n = (1.0f - ALEAK) * h1reg + ALEAK * tanhf(a);
      h1reg = h1n;
      sta(wrh + (size_t)bg * HHH + n, h1n);
      post_flag(&h1c[t]);
    }
  } else if (blk < 224) {
    // ================= H2 main =================
    const int sb_ = blk - 160;
    const int c = tid & 15, bg = tid >> 4;
    const int n = sb_ * 16 + c;
    load_w2(w4, Wmh2, Win2, sb_ * 16, tid);
    __syncthreads();
    float h2reg = 0.f;  // this thread's own h2[bg][n]
    for (int t = 0; t < TT; ++t) {
      float* wrh = h2s + ((t & 1) ^ 1) * BB * HHH;
      const float* rdm2 = m2s + ((t & 1) ^ 1) * BB * MM;   // m2_new
      const float* rdh1 = h1s + ((t & 1) ^ 1) * BB * HHH;  // h1_new
      wait_flag(&m2c[t], 64);
      float a = matdot16(rdm2, w4, sbuf, tid);        // Wmh2 part
      wait_flag(&h1c[t], 64);
      a += matdot16(rdh1, w4 + 4096, sbuf, tid);      // Win2 part
      wait_flag(&g2c[t], 32);
      a += lda(g2a + (size_t)bg * HHH + n);
      float h2n = (1.0f - ALEAK) * h2reg + ALEAK * tanhf(a);
      h2reg = h2n;
      sta(wrh + (size_t)bg * HHH + n, h2n);
      out[((size_t)bg * TT + t) * HHH + n] = h2n;  // plain store; visible at kernel end
      post_flag(&h2c[t]);
    }
  } else {
    // ================= G2 (Wh2 partial) =================
    const int sb_ = blk - 224;
    const int c = tid & 31;
    const int n = sb_ * 32 + c;
    const int r0 = tid >> 5, r1 = r0 + 16;
    load_w1(w4, Wh2, sb_ * 32, tid);
    __syncthreads();
    const float bias = b2[n];
    for (int t = 0; t < TT; ++t) {
      const float* rdh = h2s + (t & 1) * BB * HHH;  // h2_old
      if (t >= 1) wait_flag(&h2c[t - 1], 64);  // also: consumer of g2a done
      float a0 = bias, a1 = bias;
      matdot32(rdh, w4, sbuf, tid, a0, a1);
      sta(g2a + (size_t)r0 * HHH + n, a0);
      sta(g2a + (size_t)r1 * HHH + n, a1);
      post_flag(&g2c[t]);
    }
  }
}

extern "C" void kernel_launch(void* const* d_in, const int* in_sizes, int n_in,
                              void* d_out, int out_size, void* d_ws,
                              size_t ws_size, hipStream_t stream) {
  const float* xin  = (const float*)d_in[0];
  const float* Wm1  = (const float*)d_in[1];
  const float* Vm1  = (const float*)d_in[2];
  const float* Wm2  = (const float*)d_in[3];
  const float* Vm2  = (const float*)d_in[4];
  const float* Win1 = (const float*)d_in[5];
  const float* Wh1  = (const float*)d_in[6];
  const float* Wmh1 = (const float*)d_in[7];
  const float* b1   = (const float*)d_in[8];
  const float* Win2 = (const float*)d_in[9];
  const float* Wh2  = (const float*)d_in[10];
  const float* Wmh2 = (const float*)d_in[11];
  const float* b2   = (const float*)d_in[12];
  float* out = (float*)d_out;

  float* ws = (float*)d_ws;
  const size_t data_floats = (size_t)8 * BB * MM + (size_t)BB * HHH;  // states + g2a
  int* flags = (int*)(ws + data_floats);
  const size_t clear_bytes = data_floats * sizeof(float) + (size_t)5 * TT * sizeof(int);
  hipMemsetAsync(d_ws, 0, clear_bytes, stream);  // zero states + flags (ws is 0xAA-poisoned)

  const int lds_bytes = (8192 + 1056) * 16;  // 147968 B = 144.5 KiB
  static bool cfg = false;
  if (!cfg) {
    (void)hipFuncSetAttribute((const void*)drmn_persistent,
                              hipFuncAttributeMaxDynamicSharedMemorySize,
                              lds_bytes);
    cfg = true;
  }

  drmn_persistent<<<256, NTHREADS, lds_bytes, stream>>>(
      xin, Wm1, Vm1, Wm2, Vm2, Win1, Wh1, Wmh1, b1, Win2, Wh2, Wmh2, b2, out,
      ws, flags);
}